// Round 1
// baseline (1461.978 us; speedup 1.0000x reference)
//
#include <hip/hip_runtime.h>
#include <stdint.h>

// Problem constants
#define NROWS  65536   // 64 * 32 * 32
#define KCODES 1024
#define DDIM   256

// ---- ws layout (bytes) ----
// 0      : double lossacc
// 1024   : float counts[1024]
// 8192   : float n2e[1024]
// 16384  : float n2x[65536]
// 278528 : int   idx[65536]
// total  : 540672

__device__ __forceinline__ uint32_t rotl32(uint32_t x, uint32_t r){ return (x<<r)|(x>>(32u-r)); }

// JAX threefry2x32 (key = (0,42)), element eidx of a flat (2^26)-element draw,
// mapped to jax.random.uniform(minval=1e-9, maxval=1.0) then Gumbel(-log(-log(u))).
__device__ __forceinline__ float gumbel_of(uint32_t eidx){
  const uint32_t HALF = 33554432u;            // 2^26 / 2
  const uint32_t ks0 = 0u, ks1 = 42u, ks2 = 0x1BD11BDAu ^ 42u;
  const bool lo = (eidx < HALF);
  uint32_t x0 = lo ? eidx : (eidx - HALF);
  uint32_t x1 = x0 + HALF;
  x0 += ks0; x1 += ks1;
#define TF_R(rr) { x0 += x1; x1 = rotl32(x1, rr); x1 ^= x0; }
  TF_R(13) TF_R(15) TF_R(26) TF_R(6)   x0 += ks1; x1 += ks2 + 1u;
  TF_R(17) TF_R(29) TF_R(16) TF_R(24)  x0 += ks2; x1 += ks0 + 2u;
  TF_R(13) TF_R(15) TF_R(26) TF_R(6)   x0 += ks0; x1 += ks1 + 3u;
  TF_R(17) TF_R(29) TF_R(16) TF_R(24)  x0 += ks1; x1 += ks2 + 4u;
  TF_R(13) TF_R(15) TF_R(26) TF_R(6)   x0 += ks2; x1 += ks0 + 5u;
#undef TF_R
  uint32_t bits = lo ? x0 : x1;
  float f = __uint_as_float((bits >> 9) | 0x3f800000u) - 1.0f;  // [0, 1-2^-23]
  float u = fmaxf(1e-9f, f + 1e-9f);   // (maxval-minval) rounds to 1.0f in f32
  return -logf(-logf(u));
}

extern "C" __global__ void __launch_bounds__(1024) k_init(float* counts, double* lossacc){
  int t = threadIdx.x;
  if (t < KCODES) counts[t] = 0.f;
  if (t == 0) *lossacc = 0.0;
}

// ||e_k||^2 in f64 -> f32. One wave per code.
extern "C" __global__ void __launch_bounds__(256) k_n2e(const float* __restrict__ emb,
                                                        float* __restrict__ n2e){
  int w = threadIdx.x >> 6, l = threadIdx.x & 63;
  int c = blockIdx.x * 4 + w;
  double acc = 0.0;
  #pragma unroll
  for (int jj=0; jj<4; jj++){
    float v = emb[c*DDIM + l + 64*jj];
    acc += (double)v * (double)v;
  }
  #pragma unroll
  for (int off=32; off>0; off>>=1) acc += __shfl_down(acc, off);
  if (l == 0) n2e[c] = (float)acc;
}

// ||x_n||^2 in f64 -> f32. Coalesced: thread n walks d with stride 1024.
extern "C" __global__ void __launch_bounds__(256) k_n2x(const float* __restrict__ in,
                                                        float* __restrict__ n2x){
  int n = blockIdx.x * 256 + threadIdx.x;
  int b = n >> 10, hw = n & 1023;
  const float* p = in + (size_t)b * (DDIM*1024) + hw;
  double acc = 0.0;
  for (int d=0; d<DDIM; d++){
    float v = p[(size_t)d*1024];
    acc += (double)v * (double)v;
  }
  n2x[n] = (float)acc;
}

// Main fused kernel: f32 GEMM tile (32 rows x 1024 codes per WG) + per-row
// argmax(-d2+gumbel) with first-index tie-break + softmax entropy.
extern "C" __global__ void __launch_bounds__(256) k_main(
    const float* __restrict__ in, const float* __restrict__ emb,
    const float* __restrict__ n2x, const float* __restrict__ n2e,
    int* __restrict__ idxb, float* __restrict__ counts, double* __restrict__ lossacc)
{
  __shared__ float Bs[8*KCODES];   // 32 KB; reused as sbuf[16][256] in epilogue
  __shared__ float As[8*32];       // 1 KB
  __shared__ float n2es[KCODES];   // 4 KB
  const int tid = threadIdx.x;
  const int w = tid >> 6, l = tid & 63;
  const int row0 = blockIdx.x * 32;
  const int b = row0 >> 10, hw0 = row0 & 1023;

  for (int i = tid; i < KCODES; i += 256) n2es[i] = n2e[i];

  float acc[8][16];
  #pragma unroll
  for (int r=0;r<8;r++)
    #pragma unroll
    for (int j=0;j<16;j++) acc[r][j] = 0.f;

  // K-loop over d in steps of 8; accumulation order is strictly d-ascending
  // per output (one fmaf chain) to mimic a sequential-k reference GEMM.
  for (int d0=0; d0<DDIM; d0+=8){
    __syncthreads();
    #pragma unroll
    for (int jj=0; jj<4; jj++){
      int c = tid + jj*256;
      const float4* p4 = (const float4*)(emb + (size_t)c*DDIM + d0);
      float4 v0 = p4[0], v1 = p4[1];
      Bs[0*KCODES+c]=v0.x; Bs[1*KCODES+c]=v0.y; Bs[2*KCODES+c]=v0.z; Bs[3*KCODES+c]=v0.w;
      Bs[4*KCODES+c]=v1.x; Bs[5*KCODES+c]=v1.y; Bs[6*KCODES+c]=v1.z; Bs[7*KCODES+c]=v1.w;
    }
    {
      int dd = tid >> 5, rr = tid & 31;
      As[dd*32 + rr] = in[((size_t)(b*DDIM + d0 + dd))*1024 + hw0 + rr];
    }
    __syncthreads();
    #pragma unroll
    for (int dd=0; dd<8; dd++){
      float a[8], bb[16];
      const float4* ap = (const float4*)&As[dd*32 + w*8];
      float4 a0 = ap[0], a1 = ap[1];
      a[0]=a0.x; a[1]=a0.y; a[2]=a0.z; a[3]=a0.w;
      a[4]=a1.x; a[5]=a1.y; a[6]=a1.z; a[7]=a1.w;
      #pragma unroll
      for (int j=0;j<16;j++) bb[j] = Bs[dd*KCODES + l + 64*j];
      #pragma unroll
      for (int r=0;r<8;r++)
        #pragma unroll
        for (int j=0;j<16;j++)
          acc[r][j] = fmaf(a[r], bb[j], acc[r][j]);
    }
  }
  __syncthreads();   // all waves done reading Bs; reuse as per-thread s-buffer

  float* sbuf = Bs;  // sbuf[j*256 + tid], column private per thread
  const float LOG1EM8 = -18.420680743952367f;  // log(1e-8)

  #pragma unroll
  for (int r=0; r<8; r++){
    const int n = row0 + w*8 + r;
    const float n2xv = n2x[n];
    // s = -d2, composed in the reference's f32 op order:
    // t = fl(n2x + n2e); d2 = fl(t - fl(2*dot)); s = -d2 (exact)
    #pragma unroll
    for (int j=0;j<16;j++){
      int c = l + 64*j;
      float t = n2xv + n2es[c];
      float d2 = t - 2.0f*acc[r][j];
      sbuf[j*256 + tid] = -d2;
    }
    // pass A: argmax(s + gumbel) (first-index tie-break) and max(s)
    float zb = -INFINITY; int cb = 0; float ms = -INFINITY;
    for (int j=0;j<16;j++){
      float s = sbuf[j*256 + tid];
      int c = l + 64*j;
      float g = gumbel_of((uint32_t)n*1024u + (uint32_t)c);
      float z = s + g;                 // fl(-d2 + g), matches reference
      if (z > zb){ zb = z; cb = c; }   // j ascending => keeps lowest c per lane
      ms = fmaxf(ms, s);
    }
    #pragma unroll
    for (int off=1; off<64; off<<=1){
      float oz = __shfl_xor(zb, off);
      int   oc = __shfl_xor(cb, off);
      if (oz > zb || (oz == zb && oc < cb)){ zb = oz; cb = oc; }
      ms = fmaxf(ms, __shfl_xor(ms, off));
    }
    // pass B: Z and sum t*e for entropy  (loss is a tolerant scalar mean)
    float E = 0.f, SE = 0.f;
    for (int j=0;j<16;j++){
      float t = sbuf[j*256 + tid] - ms;
      float e = __expf(t);
      E += e; SE = fmaf(t, e, SE);
    }
    #pragma unroll
    for (int off=1; off<64; off<<=1){ E += __shfl_xor(E, off); SE += __shfl_xor(SE, off); }
    float logZ = logf(E);
    float H = SE/E - logZ;             // sum_k p*log p (unclipped part)
    // clip correction: elements with 0 < p < 1e-8 use log(1e-8)
    float corr = 0.f;
    float sth = ms + logZ + LOG1EM8 + 1.0f;   // coarse guard, exact test inside
    for (int j=0;j<16;j++){
      float s = sbuf[j*256 + tid];
      if (s < sth){
        float e = __expf(s - ms);
        float p = e / E;
        if (p > 0.f && p < 1e-8f) corr += p * (LOG1EM8 - (s - ms - logZ));
      }
    }
    #pragma unroll
    for (int off=1; off<64; off<<=1) corr += __shfl_xor(corr, off);
    H += corr;
    if (l == 0){
      idxb[n] = cb;
      atomicAdd(&counts[cb], 1.0f);
      atomicAdd(lossacc, (double)H);
    }
  }
}

// q_out[b,d,h,w] = emb[idx[n], d]; one block per (b,d), thread = hw. Writes coalesced.
extern "C" __global__ void __launch_bounds__(1024) k_gather(const float* __restrict__ emb,
                                                            const int* __restrict__ idxb,
                                                            float* __restrict__ out){
  int bd = blockIdx.x;            // b*256 + d
  int hw = threadIdx.x;
  int b = bd >> 8, d = bd & 255;
  int row = idxb[b*1024 + hw];
  out[1 + (size_t)bd*1024 + hw] = emb[(size_t)row*DDIM + d];
}

extern "C" __global__ void __launch_bounds__(1024) k_final(const float* __restrict__ counts,
                                                           const double* __restrict__ lossacc,
                                                           float* __restrict__ out){
  __shared__ float red[16];
  int t = threadIdx.x;
  float avg = counts[t] * (1.0f/65536.0f);        // exact (int / 2^16)
  float term = avg * logf(avg + 1e-10f);          // avg==0 contributes 0
  #pragma unroll
  for (int off=1; off<64; off<<=1) term += __shfl_xor(term, off);
  if ((t & 63) == 0) red[t >> 6] = term;
  __syncthreads();
  if (t == 0){
    float s = 0.f;
    #pragma unroll
    for (int i=0;i<16;i++) s += red[i];
    out[16777217] = expf(-s);                     // perplexity
    double m = *lossacc / 65536.0;
    out[0] = (float)(0.25 * m);                   // COMMITMENT_COST * mean
  }
}

extern "C" void kernel_launch(void* const* d_in, const int* in_sizes, int n_in,
                              void* d_out, int out_size, void* d_ws, size_t ws_size,
                              hipStream_t stream){
  const float* in  = (const float*)d_in[0];   // [64,256,32,32]
  const float* emb = (const float*)d_in[1];   // [1024,256]
  float* out = (float*)d_out;                 // [1 + 16777216 + 1]
  char* ws = (char*)d_ws;
  double* lossacc = (double*)(ws + 0);
  float*  counts  = (float*) (ws + 1024);
  float*  n2e     = (float*) (ws + 8192);
  float*  n2x     = (float*) (ws + 16384);
  int*    idxb    = (int*)   (ws + 278528);

  k_init  <<<dim3(1),     dim3(1024), 0, stream>>>(counts, lossacc);
  k_n2e   <<<dim3(256),   dim3(256),  0, stream>>>(emb, n2e);
  k_n2x   <<<dim3(256),   dim3(256),  0, stream>>>(in, n2x);
  k_main  <<<dim3(2048),  dim3(256),  0, stream>>>(in, emb, n2x, n2e, idxb, counts, lossacc);
  k_gather<<<dim3(16384), dim3(1024), 0, stream>>>(emb, idxb, out);
  k_final <<<dim3(1),     dim3(1024), 0, stream>>>(counts, lossacc, out);
}

// Round 5
// 666.117 us; speedup vs baseline: 2.1948x; 2.1948x over previous
//
#include <hip/hip_runtime.h>
#include <stdint.h>

#define NROWS  65536
#define KCODES 1024
#define DDIM   256

// ---- ws layout (bytes) ----
// 0       : double lossacc
// 1024    : float counts[1024]
// 8192    : float n2e[1024]
// 16384   : float n2x[65536]            (256KB)
// 278528  : int   idx[65536]            (256KB)
// 589824  : ushort ehi[8][1024][32]     (512KB, K-step-tiled bf16 hi)
// 1114112 : ushort elo[8][1024][32]     (512KB, bf16 lo)
// end 1638400

typedef short short8 __attribute__((ext_vector_type(8)));
typedef float f32x4  __attribute__((ext_vector_type(4)));

__device__ __forceinline__ uint32_t rotl32(uint32_t x, uint32_t r){ return (x<<r)|(x>>(32u-r)); }

// JAX threefry2x32, key=(0,42), counter pair (e0, e0+2^25). o0 -> element e0,
// o1 -> element e0+2^25 of the flat 2^26 draw (rows n and n+32768 share a call).
__device__ __forceinline__ void tf2(uint32_t e0, uint32_t& o0, uint32_t& o1){
  const uint32_t ks0 = 0u, ks1 = 42u, ks2 = 0x1BD11BDAu ^ 42u;
  uint32_t x0 = e0, x1 = e0 + 33554432u;
  x0 += ks0; x1 += ks1;
#define TF_R(rr) { x0 += x1; x1 = rotl32(x1, rr); x1 ^= x0; }
  TF_R(13) TF_R(15) TF_R(26) TF_R(6)   x0 += ks1; x1 += ks2 + 1u;
  TF_R(17) TF_R(29) TF_R(16) TF_R(24)  x0 += ks2; x1 += ks0 + 2u;
  TF_R(13) TF_R(15) TF_R(26) TF_R(6)   x0 += ks0; x1 += ks1 + 3u;
  TF_R(17) TF_R(29) TF_R(16) TF_R(24)  x0 += ks1; x1 += ks2 + 4u;
  TF_R(13) TF_R(15) TF_R(26) TF_R(6)   x0 += ks2; x1 += ks0 + 5u;
#undef TF_R
  o0 = x0; o1 = x1;
}

__device__ __forceinline__ float gum(uint32_t bits){
  float f = __uint_as_float((bits >> 9) | 0x3f800000u) - 1.0f;  // [0,1-2^-23]
  float u = fmaxf(1e-9f, f + 1e-9f);
  return -logf(-logf(u));
}

__device__ __forceinline__ unsigned short bf16rne(float x){
  uint32_t u = __float_as_uint(x);
  return (unsigned short)((u + 0x7FFFu + ((u >> 16) & 1u)) >> 16);
}
__device__ __forceinline__ float bf2f(unsigned short h){ return __uint_as_float(((uint32_t)h) << 16); }

__device__ __forceinline__ void gld16(const void* g, void* l){
  __builtin_amdgcn_global_load_lds((const __attribute__((address_space(1))) uint32_t*)g,
                                   (__attribute__((address_space(3))) uint32_t*)l, 16, 0, 0);
}

extern "C" __global__ void __launch_bounds__(1024) k_init(float* counts, double* lossacc){
  int t = threadIdx.x;
  if (t < KCODES) counts[t] = 0.f;
  if (t == 0) *lossacc = 0.0;
}

// emb -> bf16 hi/lo, K-step-tiled [d>>5][code][d&31] so B staging is a linear copy.
extern "C" __global__ void __launch_bounds__(512) k_split(const float* __restrict__ emb,
    unsigned short* __restrict__ ehi, unsigned short* __restrict__ elo){
  int e = blockIdx.x * 512 + threadIdx.x;   // grid 512 -> 262144
  float v = emb[e];
  unsigned short h = bf16rne(v);
  unsigned short lo2 = bf16rne(v - bf2f(h));
  int c = e >> 8, d = e & 255;
  int dst = (d >> 5) * 32768 + c * 32 + (d & 31);
  ehi[dst] = h; elo[dst] = lo2;
}

extern "C" __global__ void __launch_bounds__(256) k_n2e(const float* __restrict__ emb,
                                                        float* __restrict__ n2e){
  int w = threadIdx.x >> 6, l = threadIdx.x & 63;
  int c = blockIdx.x * 4 + w;
  double acc = 0.0;
  #pragma unroll
  for (int jj=0; jj<4; jj++){
    float v = emb[c*DDIM + l + 64*jj];
    acc += (double)v * (double)v;
  }
  #pragma unroll
  for (int off=32; off>0; off>>=1) acc += __shfl_down(acc, off);
  if (l == 0) n2e[c] = (float)acc;
}

extern "C" __global__ void __launch_bounds__(256) k_n2x(const float* __restrict__ in,
                                                        float* __restrict__ n2x){
  int n = blockIdx.x * 256 + threadIdx.x;
  int b = n >> 10, hw = n & 1023;
  const float* p = in + (size_t)b * (DDIM*1024) + hw;
  double acc = 0.0;
  for (int d=0; d<DDIM; d++){
    float v = p[(size_t)d*1024];
    acc += (double)v * (double)v;
  }
  n2x[n] = (float)acc;
}

// Fused MFMA GEMM (3-term bf16 split) + gumbel-argmax + entropy.
// Block: rows {row0..row0+31} U {row0+32768..+31}, all 1024 codes. 8 waves.
// Wave w: all 4 row-tiles x col-tiles [w*128, w*128+128).
extern "C" __global__ void __launch_bounds__(512, 2) k_main(
    const float* __restrict__ in,
    const unsigned short* __restrict__ ehi, const unsigned short* __restrict__ elo,
    const float* __restrict__ n2x, const float* __restrict__ n2e,
    int* __restrict__ idxb, float* __restrict__ counts, double* __restrict__ lossacc)
{
  __shared__ __align__(16) unsigned short BufH[1024*32];   // 64KB, reused as sbuf
  __shared__ __align__(16) unsigned short BufL[1024*32];   // 64KB
  __shared__ __align__(16) unsigned short AhiS[64*40];     // 5KB (rows padded to 40 halves)
  __shared__ __align__(16) unsigned short AloS[64*40];     // 5KB
  __shared__ float n2es[1024];

  const int t = threadIdx.x;
  const int w = t >> 6, l = t & 63;
  const int row0 = blockIdx.x * 32;
  const int b1 = row0 >> 10;
  const int hw0 = row0 & 1023;
  const int wc = w * 128;

  for (int i = t; i < 1024; i += 512) n2es[i] = n2e[i];

  f32x4 acc[4][8];
  #pragma unroll
  for (int rt=0; rt<4; rt++)
    #pragma unroll
    for (int ct=0; ct<8; ct++)
      acc[rt][ct] = (f32x4){0.f,0.f,0.f,0.f};

  for (int ks = 0; ks < 8; ks++){
    __syncthreads();
    // stage B hi+lo (linear global_load_lds, tiles are pre-linearized)
    {
      const char* gH = (const char*)ehi + (size_t)ks * 65536;
      const char* gL = (const char*)elo + (size_t)ks * 65536;
      #pragma unroll
      for (int i2 = 0; i2 < 8; i2++){
        int off = (w*8 + i2) * 1024;
        gld16(gH + off + l*16, (char*)BufH + off);
        gld16(gL + off + l*16, (char*)BufL + off);
      }
    }
    // stage A (on-the-fly bf16 split), row = lane, d-col = w + 8*i
    {
      int row = l;
      int s2f = (row >= 32);
      int b = b1 + (s2f ? 32 : 0);
      int hw = hw0 + row - (s2f ? 32 : 0);
      #pragma unroll
      for (int i2 = 0; i2 < 4; i2++){
        int dd = w + 8*i2;
        float v = in[((size_t)(b*256 + ks*32 + dd))*1024 + hw];
        unsigned short h = bf16rne(v);
        unsigned short lo2 = bf16rne(v - bf2f(h));
        AhiS[row*40 + dd] = h;
        AloS[row*40 + dd] = lo2;
      }
    }
    __syncthreads();
    short8 ah[4], al[4], bh[8];
    #pragma unroll
    for (int rt=0; rt<4; rt++){
      ah[rt] = *(const short8*)&AhiS[(rt*16 + (l&15))*40 + (l>>4)*8];
      al[rt] = *(const short8*)&AloS[(rt*16 + (l&15))*40 + (l>>4)*8];
    }
    #pragma unroll
    for (int ct=0; ct<8; ct++)
      bh[ct] = *(const short8*)&BufH[(wc + ct*16 + (l&15))*32 + (l>>4)*8];
    #pragma unroll
    for (int ct=0; ct<8; ct++)
      #pragma unroll
      for (int rt=0; rt<4; rt++)
        acc[rt][ct] = __builtin_amdgcn_mfma_f32_16x16x32_bf16(ah[rt], bh[ct], acc[rt][ct], 0, 0, 0);
    #pragma unroll
    for (int ct=0; ct<8; ct++)
      #pragma unroll
      for (int rt=0; rt<4; rt++)
        acc[rt][ct] = __builtin_amdgcn_mfma_f32_16x16x32_bf16(al[rt], bh[ct], acc[rt][ct], 0, 0, 0);
    #pragma unroll
    for (int ct=0; ct<8; ct++){
      short8 bl = *(const short8*)&BufL[(wc + ct*16 + (l&15))*32 + (l>>4)*8];
      #pragma unroll
      for (int rt=0; rt<4; rt++)
        acc[rt][ct] = __builtin_amdgcn_mfma_f32_16x16x32_bf16(ah[rt], bl, acc[rt][ct], 0, 0, 0);
    }
  }

  // ---- epilogue: 4 groups of 8 row-pairs (n, n+32768) ----
  float* sbuf = (float*)BufH;   // 16 rows x 1024 f32 = 64KB
  const float LOG1EM8 = -18.420680743952367f;
  #pragma unroll
  for (int g=0; g<4; g++){
    __syncthreads();
    {
      int fr = l >> 4;
      if ((fr >> 1) == (g & 1)){
        const int rtA = g >> 1, rtB = 2 + (g >> 1);
        int base = (fr & 1) * 4;
        #pragma unroll
        for (int ct=0; ct<8; ct++){
          int col = wc + ct*16 + (l & 15);
          #pragma unroll
          for (int r=0; r<4; r++){
            sbuf[(base+r)*1024 + col]   = acc[rtA][ct][r];   // strip1 -> rows 0..7
            sbuf[(8+base+r)*1024 + col] = acc[rtB][ct][r];   // strip2 -> rows 8..15
          }
        }
      }
    }
    __syncthreads();
    {
      const int n1 = row0 + g*8 + w;
      const int n2v = n1 + 32768;
      float* s1 = sbuf + w*1024;
      float* s2 = sbuf + (8+w)*1024;
      const float x1n = n2x[n1], x2n = n2x[n2v];
      float zb1=-INFINITY, zb2=-INFINITY; int cb1=0, cb2=0;
      float ms1=-INFINITY, ms2=-INFINITY;
      for (int j=0;j<16;j++){
        int c = l + 64*j;
        float dA = s1[c], dB = s2[c];
        float sA = -((x1n + n2es[c]) - 2.0f*dA);   // reference f32 op order
        float sB = -((x2n + n2es[c]) - 2.0f*dB);
        s1[c] = sA; s2[c] = sB;
        uint32_t o0, o1; tf2((uint32_t)n1*1024u + (uint32_t)c, o0, o1);
        float z1 = sA + gum(o0), z2 = sB + gum(o1);
        if (z1 > zb1){ zb1 = z1; cb1 = c; }
        if (z2 > zb2){ zb2 = z2; cb2 = c; }
        ms1 = fmaxf(ms1, sA); ms2 = fmaxf(ms2, sB);
      }
      #pragma unroll
      for (int off=1; off<64; off<<=1){
        float oz = __shfl_xor(zb1, off); int oc = __shfl_xor(cb1, off);
        if (oz > zb1 || (oz == zb1 && oc < cb1)){ zb1 = oz; cb1 = oc; }
        oz = __shfl_xor(zb2, off); oc = __shfl_xor(cb2, off);
        if (oz > zb2 || (oz == zb2 && oc < cb2)){ zb2 = oz; cb2 = oc; }
        ms1 = fmaxf(ms1, __shfl_xor(ms1, off));
        ms2 = fmaxf(ms2, __shfl_xor(ms2, off));
      }
      float E1=0.f, SE1=0.f, E2=0.f, SE2=0.f;
      for (int j=0;j<16;j++){
        int c = l + 64*j;
        float t1 = s1[c] - ms1; float e1 = __expf(t1); E1 += e1; SE1 = fmaf(t1, e1, SE1);
        float t2 = s2[c] - ms2; float e2 = __expf(t2); E2 += e2; SE2 = fmaf(t2, e2, SE2);
      }
      #pragma unroll
      for (int off=1; off<64; off<<=1){
        E1 += __shfl_xor(E1, off); SE1 += __shfl_xor(SE1, off);
        E2 += __shfl_xor(E2, off); SE2 += __shfl_xor(SE2, off);
      }
      float lz1 = logf(E1), lz2 = logf(E2);
      float H1 = SE1/E1 - lz1, H2 = SE2/E2 - lz2;
      float corr1 = 0.f, corr2 = 0.f;
      float th1 = ms1 + lz1 + LOG1EM8 + 1.0f;
      float th2 = ms2 + lz2 + LOG1EM8 + 1.0f;
      for (int j=0;j<16;j++){
        int c = l + 64*j;
        float sA = s1[c];
        if (sA < th1){
          float e = __expf(sA - ms1); float p = e / E1;
          if (p > 0.f && p < 1e-8f) corr1 += p * (LOG1EM8 - (sA - ms1 - lz1));
        }
        float sB = s2[c];
        if (sB < th2){
          float e = __expf(sB - ms2); float p = e / E2;
          if (p > 0.f && p < 1e-8f) corr2 += p * (LOG1EM8 - (sB - ms2 - lz2));
        }
      }
      #pragma unroll
      for (int off=1; off<64; off<<=1){ corr1 += __shfl_xor(corr1, off); corr2 += __shfl_xor(corr2, off); }
      H1 += corr1; H2 += corr2;
      if (l == 0){
        idxb[n1] = cb1; idxb[n2v] = cb2;
        atomicAdd(&counts[cb1], 1.0f);
        atomicAdd(&counts[cb2], 1.0f);
        atomicAdd(lossacc, (double)H1 + (double)H2);
      }
    }
  }
}

extern "C" __global__ void __launch_bounds__(1024) k_gather(const float* __restrict__ emb,
                                                            const int* __restrict__ idxb,
                                                            float* __restrict__ out){
  int bd = blockIdx.x;            // b*256 + d
  int hw = threadIdx.x;
  int b = bd >> 8, d = bd & 255;
  int row = idxb[b*1024 + hw];
  out[1 + (size_t)bd*1024 + hw] = emb[(size_t)row*DDIM + d];
}

extern "C" __global__ void __launch_bounds__(1024) k_final(const float* __restrict__ counts,
                                                           const double* __restrict__ lossacc,
                                                           float* __restrict__ out){
  __shared__ float red[16];
  int t = threadIdx.x;
  float avg = counts[t] * (1.0f/65536.0f);
  float term = avg * logf(avg + 1e-10f);
  #pragma unroll
  for (int off=1; off<64; off<<=1) term += __shfl_xor(term, off);
  if ((t & 63) == 0) red[t >> 6] = term;
  __syncthreads();
  if (t == 0){
    float s = 0.f;
    #pragma unroll
    for (int i=0;i<16;i++) s += red[i];
    out[16777217] = expf(-s);
    double m = *lossacc / 65536.0;
    out[0] = (float)(0.25 * m);
  }
}

extern "C" void kernel_launch(void* const* d_in, const int* in_sizes, int n_in,
                              void* d_out, int out_size, void* d_ws, size_t ws_size,
                              hipStream_t stream){
  const float* in  = (const float*)d_in[0];   // [64,256,32,32]
  const float* emb = (const float*)d_in[1];   // [1024,256]
  float* out = (float*)d_out;
  char* ws = (char*)d_ws;
  double* lossacc = (double*)(ws + 0);
  float*  counts  = (float*) (ws + 1024);
  float*  n2e     = (float*) (ws + 8192);
  float*  n2x     = (float*) (ws + 16384);
  int*    idxb    = (int*)   (ws + 278528);
  unsigned short* ehi = (unsigned short*)(ws + 589824);
  unsigned short* elo = (unsigned short*)(ws + 1114112);

  k_init  <<<dim3(1),     dim3(1024), 0, stream>>>(counts, lossacc);
  k_split <<<dim3(512),   dim3(512),  0, stream>>>(emb, ehi, elo);
  k_n2e   <<<dim3(256),   dim3(256),  0, stream>>>(emb, n2e);
  k_n2x   <<<dim3(256),   dim3(256),  0, stream>>>(in, n2x);
  k_main  <<<dim3(1024),  dim3(512),  0, stream>>>(in, ehi, elo, n2x, n2e, idxb, counts, lossacc);
  k_gather<<<dim3(16384), dim3(1024), 0, stream>>>(emb, idxb, out);
  k_final <<<dim3(1),     dim3(1024), 0, stream>>>(counts, lossacc, out);
}